// Round 2
// baseline (148.297 us; speedup 1.0000x reference)
//
#include <hip/hip_runtime.h>
#include <stdint.h>

typedef float f32x16 __attribute__((ext_vector_type(16)));
typedef short bf16x8 __attribute__((ext_vector_type(8)));
typedef uint32_t u32;

#define SIZE 784
#define NLBL 10
#define LABEL_SITE 392
#define BATCH 128
#define NSEG 56           // segments over the 784-long (cyclic) chain
#define SEGLEN 14         // 56 * 14 = 784
#define BIW 8             // batch items per wave

// ---------- helpers ----------

// round-to-nearest (half-away) fp32 -> bf16 bits, low 16 zeroed
__device__ inline u32 rnb(u32 u) { return (u + 0x8000u) & 0xffff0000u; }

// RNE-ish split of 8 fp32 (j-order) into packed bf16 hi/lo fragments.
// hi = rn_bf16(x); lo = rn_bf16(x - hi).  |x-hi| <= 2^-8|x|, lo rep err <= 2^-16.
// Pair packing: element 2p -> low 16 bits, 2p+1 -> high 16 bits.
__device__ inline void split_pack(const float s[8], u32 hi[4], u32 lo[4]) {
#pragma unroll
  for (int p = 0; p < 4; ++p) {
    u32 he = rnb(__float_as_uint(s[2 * p]));
    u32 ho = rnb(__float_as_uint(s[2 * p + 1]));
    // result bytes = {odd.b3, odd.b2, even.b3, even.b2}
    hi[p] = __builtin_amdgcn_perm(ho, he, 0x07060302u);
    float le = s[2 * p] - __uint_as_float(he);
    float lodd = s[2 * p + 1] - __uint_as_float(ho);
    u32 ge = rnb(__float_as_uint(le));
    u32 go = rnb(__float_as_uint(lodd));
    lo[p] = __builtin_amdgcn_perm(go, ge, 0x07060302u);
  }
}

__device__ inline f32x16 mfma_bb(const u32 (&a)[4], const u32 (&b)[4], f32x16 c) {
  union U { u32 u[4]; bf16x8 v; };
  U A, B;
#pragma unroll
  for (int i = 0; i < 4; ++i) { A.u[i] = a[i]; B.u[i] = b[i]; }
  return __builtin_amdgcn_mfma_f32_32x32x16_bf16(A.v, B.v, c, 0, 0, 0);
}

// Identity matrix in C/D fragment layout:
// row = (reg&3) + 8*(reg>>2) + 4*(lane>>5), col = lane&31
__device__ inline f32x16 ident_acc(int lane) {
  const int gam = lane & 31, hib = lane >> 5;
  f32x16 a;
#pragma unroll
  for (int reg = 0; reg < 16; ++reg) {
    int rho = (reg & 3) + 8 * (reg >> 2) + 4 * hib;
    a[reg] = (rho == gam) ? 1.0f : 0.0f;
  }
  return a;
}

// One chain step: X <- A_mfma * X.  A given as hi/lo bf16 frags per k-half t;
// X (=acc) is in C/D layout and is converted to B-operand frags in-register:
// B-frag slot (t,j) needs Y[rho][col] with rho = 16t + 8*hib + j, obtained
// from own regs or lane^32 partner regs (derived from the verified C/D map).
__device__ inline f32x16 chain_step(const u32 (&Ah)[2][4], const u32 (&Al)[2][4],
                                    f32x16 acc, int hib) {
  float pr[16];
#pragma unroll
  for (int q = 0; q < 16; ++q) pr[q] = __shfl_xor(acc[q], 32, 64);
  u32 Bh[2][4], Bl[2][4];
#pragma unroll
  for (int t = 0; t < 2; ++t) {
    float slot[8];
#pragma unroll
    for (int j = 0; j < 4; ++j) slot[j] = hib ? pr[8 * t + j + 4] : acc[8 * t + j];
#pragma unroll
    for (int j = 4; j < 8; ++j) slot[j] = hib ? acc[8 * t + j] : pr[8 * t + j - 4];
    split_pack(slot, Bh[t], Bl[t]);
  }
  f32x16 r;
#pragma unroll
  for (int i = 0; i < 16; ++i) r[i] = 0.0f;
  // smallest terms first
  r = mfma_bb(Al[0], Bl[0], r);
  r = mfma_bb(Al[1], Bl[1], r);
  r = mfma_bb(Ah[0], Bl[0], r);
  r = mfma_bb(Ah[1], Bl[1], r);
  r = mfma_bb(Al[0], Bh[0], r);
  r = mfma_bb(Al[1], Bh[1], r);
  r = mfma_bb(Ah[0], Bh[0], r);
  r = mfma_bb(Ah[1], Bh[1], r);
  return r;
}

// Store acc (matrix Y in C/D layout) into A-fragment layout for the next
// level: element Y[rho][gam] -> lane' = rho + 32*((gam>>3)&1), h = gam>>4,
// j = gam&7;  flat: dst[h*512 + lane'*8 + j]
__device__ inline void store_afrag(float* dst, f32x16 acc, int lane) {
  const int gam = lane & 31, hib = lane >> 5;
  const int h = gam >> 4, j = gam & 7, b5 = (gam >> 3) & 1;
#pragma unroll
  for (int reg = 0; reg < 16; ++reg) {
    int rho = (reg & 3) + 8 * (reg >> 2) + 4 * hib;
    int lp = rho + 32 * b5;
    dst[h * 512 + lp * 8 + j] = acc[reg];
  }
}

__device__ inline void load_split_afrag(const float* src, int lane,
                                        u32 (&Ah)[2][4], u32 (&Al)[2][4]) {
#pragma unroll
  for (int h = 0; h < 2; ++h) {
    const float4* p = (const float4*)(src + h * 512 + lane * 8);
    float4 q0 = p[0], q1 = p[1];
    float v[8] = {q0.x, q0.y, q0.z, q0.w, q1.x, q1.y, q1.z, q1.w};
    split_pack(v, Ah[h], Al[h]);
  }
}

// ---------- phase 1: per-segment chain products ----------
// grid = NSEG*4 blocks x 256 thr; block (g,c): 4 waves, wave handles BIW
// batch chains for segment g. Chain index ci -> site s = (392+ci)%784
// (cyclic trick: W = right@left is one 784-chain starting at site 392).
__global__ __launch_bounds__(256) void mps_phase1(const float* __restrict__ input,
                                                  const float* __restrict__ core,
                                                  float* __restrict__ wsA) {
  const int tid = threadIdx.x;
  const int w = tid >> 6, lane = tid & 63;
  const int r = lane & 31, hib = lane >> 5;
  const int g = blockIdx.x % NSEG, c = blockIdx.x / NSEG;
  const int bi0 = c * 32 + w * BIW;

  f32x16 acc[BIW];
#pragma unroll
  for (int b = 0; b < BIW; ++b) acc[b] = ident_acc(lane);

  for (int i = 0; i < SEGLEN; ++i) {
    const int ci = g * SEGLEN + i;
    const int s = (LABEL_SITE + ci) % SIZE;
    // A_mfma = M^T: element (r,k) = M[k][r] = c0[s][k][r] + x*(c1-c0)[s][k][r]
    const float* cs = core + (size_t)s * 2048 + r;
    float c0v[16], dv[16];
#pragma unroll
    for (int t = 0; t < 2; ++t)
#pragma unroll
      for (int j = 0; j < 8; ++j) {
        const int kk = 16 * t + 8 * hib + j;
        float a0 = cs[kk * 64];
        float a1 = cs[kk * 64 + 32];
        c0v[8 * t + j] = a0;
        dv[8 * t + j] = a1 - a0;
      }
#pragma unroll
    for (int b = 0; b < BIW; ++b) {
      const float x = input[(size_t)(bi0 + b) * SIZE + s];
      u32 Ah[2][4], Al[2][4];
#pragma unroll
      for (int t = 0; t < 2; ++t) {
        float m[8];
#pragma unroll
        for (int j = 0; j < 8; ++j) m[j] = fmaf(x, dv[8 * t + j], c0v[8 * t + j]);
        split_pack(m, Ah[t], Al[t]);
      }
      acc[b] = chain_step(Ah, Al, acc[b], hib);
    }
  }
#pragma unroll
  for (int b = 0; b < BIW; ++b) {
    float* dst = wsA + ((size_t)(bi0 + b) * NSEG + g) * 1024;
    store_afrag(dst, acc[b], lane);
  }
}

// ---------- phase 2a: combine 8 consecutive segment products ----------
// 896 waves: wave wid -> bi = wid&127, gg = wid>>7 (7 groups of 8 segments)
__global__ __launch_bounds__(256) void mps_phase2a(const float* __restrict__ wsA,
                                                   float* __restrict__ wsB) {
  const int tid = threadIdx.x;
  const int w = tid >> 6, lane = tid & 63;
  const int wid = blockIdx.x * 4 + w;
  const int bi = wid & 127, gg = wid >> 7;
  f32x16 acc = ident_acc(lane);
  for (int g = gg * 8; g < gg * 8 + 8; ++g) {
    u32 Ah[2][4], Al[2][4];
    load_split_afrag(wsA + ((size_t)bi * NSEG + g) * 1024, lane, Ah, Al);
    acc = chain_step(Ah, Al, acc, lane >> 5);
  }
  store_afrag(wsB + ((size_t)bi * 7 + gg) * 1024, acc, lane);
}

// ---------- phase 2b: final combine (7 groups) + trace epilogue ----------
// acc ends as W^T in C/D layout; out[b,l] = sum T[rho][l][gam]*W^T[rho][gam]
__global__ __launch_bounds__(256) void mps_phase2b(const float* __restrict__ wsB,
                                                   const float* __restrict__ label,
                                                   float* __restrict__ out) {
  const int tid = threadIdx.x;
  const int w = tid >> 6, lane = tid & 63;
  const int bi = blockIdx.x * 4 + w;
  const int gam = lane & 31, hib = lane >> 5;
  f32x16 acc = ident_acc(lane);
  for (int gg = 0; gg < 7; ++gg) {
    u32 Ah[2][4], Al[2][4];
    load_split_afrag(wsB + ((size_t)bi * 7 + gg) * 1024, lane, Ah, Al);
    acc = chain_step(Ah, Al, acc, hib);
  }
  float part[NLBL];
#pragma unroll
  for (int l = 0; l < NLBL; ++l) part[l] = 0.0f;
#pragma unroll
  for (int reg = 0; reg < 16; ++reg) {
    const int rho = (reg & 3) + 8 * (reg >> 2) + 4 * hib;
    const float wv = acc[reg];
    const float* tp = label + rho * (NLBL * 32) + gam;
#pragma unroll
    for (int l = 0; l < NLBL; ++l) part[l] = fmaf(tp[l * 32], wv, part[l]);
  }
#pragma unroll
  for (int l = 0; l < NLBL; ++l) {
#pragma unroll
    for (int mask = 32; mask >= 1; mask >>= 1)
      part[l] += __shfl_xor(part[l], mask, 64);
  }
  if (lane == 0) {
#pragma unroll
    for (int l = 0; l < NLBL; ++l) out[bi * NLBL + l] = part[l];
  }
}

extern "C" void kernel_launch(void* const* d_in, const int* in_sizes, int n_in,
                              void* d_out, int out_size, void* d_ws, size_t ws_size,
                              hipStream_t stream) {
  const float* input = (const float*)d_in[0];  // [128,784]
  const float* core  = (const float*)d_in[1];  // [784,32,2,32]
  const float* label = (const float*)d_in[2];  // [32,10,32]
  float* out = (float*)d_out;                  // [128,10]
  float* wsA = (float*)d_ws;                             // 128*56*1024 f32 = 29.4 MB
  float* wsB = wsA + (size_t)BATCH * NSEG * 1024;        // 128*7*1024 f32 = 3.7 MB

  mps_phase1<<<dim3(NSEG * 4), dim3(256), 0, stream>>>(input, core, wsA);
  mps_phase2a<<<dim3(224), dim3(256), 0, stream>>>(wsA, wsB);
  mps_phase2b<<<dim3(32), dim3(256), 0, stream>>>(wsB, label, out);
}

// Round 3
// 69.162 us; speedup vs baseline: 2.1442x; 2.1442x over previous
//
#include <hip/hip_runtime.h>
#include <stdint.h>

typedef float f32x16 __attribute__((ext_vector_type(16)));
typedef short bf16x8 __attribute__((ext_vector_type(8)));
typedef uint32_t u32;

#define SIZE 784
#define NLBL 10
#define LABEL_SITE 392
#define BATCH 128
#define NSEG 56           // segments over the 784-long (cyclic) chain
#define SEGLEN 14         // 56 * 14 = 784
#define BIW 2             // batch items per wave (small => more waves => occupancy)

// ---------- helpers ----------

// pack 2 fp32 -> 2 bf16 (RNE), elem a -> low16, elem b -> high16
__device__ inline u32 cvt_pk(float a, float b) {
  u32 r;
  asm("v_cvt_pk_bf16_f32 %0, %1, %2" : "=v"(r) : "v"(a), "v"(b));
  return r;
}

// Split 8 fp32 (j-order) into packed bf16 hi/lo fragments using RNE.
// hi = rne_bf16(x); lo = rne_bf16(x - hi). |x-hi| <= 2^-9|x| (RNE), lo rep err ~2^-17.
// Pair packing: element 2p -> low 16 bits, 2p+1 -> high 16 bits.
__device__ inline void split_pack(const float s[8], u32 hi[4], u32 lo[4]) {
#pragma unroll
  for (int p = 0; p < 4; ++p) {
    u32 h = cvt_pk(s[2 * p], s[2 * p + 1]);
    hi[p] = h;
    float he = __uint_as_float(h << 16);
    float ho = __uint_as_float(h & 0xffff0000u);
    lo[p] = cvt_pk(s[2 * p] - he, s[2 * p + 1] - ho);
  }
}

__device__ inline f32x16 mfma_bb(const u32 (&a)[4], const u32 (&b)[4], f32x16 c) {
  union U { u32 u[4]; bf16x8 v; };
  U A, B;
#pragma unroll
  for (int i = 0; i < 4; ++i) { A.u[i] = a[i]; B.u[i] = b[i]; }
  return __builtin_amdgcn_mfma_f32_32x32x16_bf16(A.v, B.v, c, 0, 0, 0);
}

// Identity matrix in C/D fragment layout:
// row = (reg&3) + 8*(reg>>2) + 4*(lane>>5), col = lane&31
__device__ inline f32x16 ident_acc(int lane) {
  const int gam = lane & 31, hib = lane >> 5;
  f32x16 a;
#pragma unroll
  for (int reg = 0; reg < 16; ++reg) {
    int rho = (reg & 3) + 8 * (reg >> 2) + 4 * hib;
    a[reg] = (rho == gam) ? 1.0f : 0.0f;
  }
  return a;
}

// One chain step: X <- A_mfma * X.  A given as hi/lo bf16 frags per k-half t;
// X (=acc) is in C/D layout and is converted to B-operand frags in-register:
// B-frag slot (t,j) needs Y[rho][col] with rho = 16t + 8*hib + j, obtained
// from own regs or lane^32 partner regs (derived from the verified C/D map).
__device__ inline f32x16 chain_step(const u32 (&Ah)[2][4], const u32 (&Al)[2][4],
                                    f32x16 acc, int hib) {
  float pr[16];
#pragma unroll
  for (int q = 0; q < 16; ++q) pr[q] = __shfl_xor(acc[q], 32, 64);
  u32 Bh[2][4], Bl[2][4];
#pragma unroll
  for (int t = 0; t < 2; ++t) {
    float slot[8];
#pragma unroll
    for (int j = 0; j < 4; ++j) slot[j] = hib ? pr[8 * t + j + 4] : acc[8 * t + j];
#pragma unroll
    for (int j = 4; j < 8; ++j) slot[j] = hib ? acc[8 * t + j] : pr[8 * t + j - 4];
    split_pack(slot, Bh[t], Bl[t]);
  }
  f32x16 r;
#pragma unroll
  for (int i = 0; i < 16; ++i) r[i] = 0.0f;
  // smallest terms first
  r = mfma_bb(Al[0], Bl[0], r);
  r = mfma_bb(Al[1], Bl[1], r);
  r = mfma_bb(Ah[0], Bl[0], r);
  r = mfma_bb(Ah[1], Bl[1], r);
  r = mfma_bb(Al[0], Bh[0], r);
  r = mfma_bb(Al[1], Bh[1], r);
  r = mfma_bb(Ah[0], Bh[0], r);
  r = mfma_bb(Ah[1], Bh[1], r);
  return r;
}

// Store acc (matrix Y in C/D layout) into A-fragment layout for the next
// level: element Y[rho][gam] -> lane' = rho + 32*((gam>>3)&1), h = gam>>4,
// j = gam&7;  flat: dst[h*512 + lane'*8 + j]
__device__ inline void store_afrag(float* dst, f32x16 acc, int lane) {
  const int gam = lane & 31, hib = lane >> 5;
  const int h = gam >> 4, j = gam & 7, b5 = (gam >> 3) & 1;
#pragma unroll
  for (int reg = 0; reg < 16; ++reg) {
    int rho = (reg & 3) + 8 * (reg >> 2) + 4 * hib;
    int lp = rho + 32 * b5;
    dst[h * 512 + lp * 8 + j] = acc[reg];
  }
}

__device__ inline void load_split_afrag(const float* src, int lane,
                                        u32 (&Ah)[2][4], u32 (&Al)[2][4]) {
#pragma unroll
  for (int h = 0; h < 2; ++h) {
    const float4* p = (const float4*)(src + h * 512 + lane * 8);
    float4 q0 = p[0], q1 = p[1];
    float v[8] = {q0.x, q0.y, q0.z, q0.w, q1.x, q1.y, q1.z, q1.w};
    split_pack(v, Ah[h], Al[h]);
  }
}

// ---------- phase 1: per-segment chain products ----------
// grid = NSEG*16 blocks x 256 thr; block (g,c): 4 waves, wave handles BIW=2
// batch chains for segment g. Chain index ci -> site s = (392+ci)%784
// (cyclic trick: W = right@left is one 784-chain starting at site 392).
__global__ __launch_bounds__(256) void mps_phase1(const float* __restrict__ input,
                                                  const float* __restrict__ core,
                                                  float* __restrict__ wsA) {
  const int tid = threadIdx.x;
  const int w = tid >> 6, lane = tid & 63;
  const int r = lane & 31, hib = lane >> 5;
  const int g = blockIdx.x % NSEG, c = blockIdx.x / NSEG;
  const int bi0 = c * (4 * BIW) + w * BIW;

  f32x16 acc[BIW];
#pragma unroll
  for (int b = 0; b < BIW; ++b) acc[b] = ident_acc(lane);

  for (int i = 0; i < SEGLEN; ++i) {
    const int ci = g * SEGLEN + i;
    const int s = (LABEL_SITE + ci) % SIZE;
    // A_mfma = M^T: element (r,k) = M[k][r] = c0[s][k][r] + x*(c1-c0)[s][k][r]
    const float* cs = core + (size_t)s * 2048 + r;
    float c0v[16], dv[16];
#pragma unroll
    for (int t = 0; t < 2; ++t)
#pragma unroll
      for (int j = 0; j < 8; ++j) {
        const int kk = 16 * t + 8 * hib + j;
        float a0 = cs[kk * 64];
        float a1 = cs[kk * 64 + 32];
        c0v[8 * t + j] = a0;
        dv[8 * t + j] = a1 - a0;
      }
#pragma unroll
    for (int b = 0; b < BIW; ++b) {
      const float x = input[(size_t)(bi0 + b) * SIZE + s];
      u32 Ah[2][4], Al[2][4];
#pragma unroll
      for (int t = 0; t < 2; ++t) {
        float m[8];
#pragma unroll
        for (int j = 0; j < 8; ++j) m[j] = fmaf(x, dv[8 * t + j], c0v[8 * t + j]);
        split_pack(m, Ah[t], Al[t]);
      }
      acc[b] = chain_step(Ah, Al, acc[b], hib);
    }
  }
#pragma unroll
  for (int b = 0; b < BIW; ++b) {
    float* dst = wsA + ((size_t)(bi0 + b) * NSEG + g) * 1024;
    store_afrag(dst, acc[b], lane);
  }
}

// ---------- phase 2a: combine 8 consecutive segment products ----------
// 896 waves: wave wid -> bi = wid&127, gg = wid>>7 (7 groups of 8 segments)
__global__ __launch_bounds__(256) void mps_phase2a(const float* __restrict__ wsA,
                                                   float* __restrict__ wsB) {
  const int tid = threadIdx.x;
  const int w = tid >> 6, lane = tid & 63;
  const int wid = blockIdx.x * 4 + w;
  const int bi = wid & 127, gg = wid >> 7;
  f32x16 acc = ident_acc(lane);
  for (int g = gg * 8; g < gg * 8 + 8; ++g) {
    u32 Ah[2][4], Al[2][4];
    load_split_afrag(wsA + ((size_t)bi * NSEG + g) * 1024, lane, Ah, Al);
    acc = chain_step(Ah, Al, acc, lane >> 5);
  }
  store_afrag(wsB + ((size_t)bi * 7 + gg) * 1024, acc, lane);
}

// ---------- phase 2b: final combine (7 groups) + trace epilogue ----------
// acc ends as W^T in C/D layout; out[b,l] = sum T[rho][l][gam]*W^T[rho][gam]
__global__ __launch_bounds__(256) void mps_phase2b(const float* __restrict__ wsB,
                                                   const float* __restrict__ label,
                                                   float* __restrict__ out) {
  const int tid = threadIdx.x;
  const int w = tid >> 6, lane = tid & 63;
  const int bi = blockIdx.x * 4 + w;
  const int gam = lane & 31, hib = lane >> 5;
  f32x16 acc = ident_acc(lane);
  for (int gg = 0; gg < 7; ++gg) {
    u32 Ah[2][4], Al[2][4];
    load_split_afrag(wsB + ((size_t)bi * 7 + gg) * 1024, lane, Ah, Al);
    acc = chain_step(Ah, Al, acc, hib);
  }
  float part[NLBL];
#pragma unroll
  for (int l = 0; l < NLBL; ++l) part[l] = 0.0f;
#pragma unroll
  for (int reg = 0; reg < 16; ++reg) {
    const int rho = (reg & 3) + 8 * (reg >> 2) + 4 * hib;
    const float wv = acc[reg];
    const float* tp = label + rho * (NLBL * 32) + gam;
#pragma unroll
    for (int l = 0; l < NLBL; ++l) part[l] = fmaf(tp[l * 32], wv, part[l]);
  }
#pragma unroll
  for (int l = 0; l < NLBL; ++l) {
#pragma unroll
    for (int mask = 32; mask >= 1; mask >>= 1)
      part[l] += __shfl_xor(part[l], mask, 64);
  }
  if (lane == 0) {
#pragma unroll
    for (int l = 0; l < NLBL; ++l) out[bi * NLBL + l] = part[l];
  }
}

extern "C" void kernel_launch(void* const* d_in, const int* in_sizes, int n_in,
                              void* d_out, int out_size, void* d_ws, size_t ws_size,
                              hipStream_t stream) {
  const float* input = (const float*)d_in[0];  // [128,784]
  const float* core  = (const float*)d_in[1];  // [784,32,2,32]
  const float* label = (const float*)d_in[2];  // [32,10,32]
  float* out = (float*)d_out;                  // [128,10]
  float* wsA = (float*)d_ws;                             // 128*56*1024 f32 = 29.4 MB
  float* wsB = wsA + (size_t)BATCH * NSEG * 1024;        // 128*7*1024 f32 = 3.7 MB

  mps_phase1<<<dim3(NSEG * (BATCH / (4 * BIW))), dim3(256), 0, stream>>>(input, core, wsA);
  mps_phase2a<<<dim3(224), dim3(256), 0, stream>>>(wsA, wsB);
  mps_phase2b<<<dim3(32), dim3(256), 0, stream>>>(wsB, label, out);
}